// Round 1
// baseline (505.042 us; speedup 1.0000x reference)
//
#include <hip/hip_runtime.h>
#include <math.h>

#define BB 256
#define NN 1024
#define KK 64
#define EE 128
#define TN 32

// ---------------- prep: per-batch combined matrix M, bias, t_abc ----------------
// C = adj @ (w_real + i w_imag)  (K x K complex)
// M (128x128): [[Cr, Ci], [-Ci, Cr]]   so  x_pre = [cos|sin] @ M + [br|bi]
__global__ __launch_bounds__(256) void prep_kernel(
    const float* __restrict__ recip,      // B*9
    const int* __restrict__ space_group,  // B
    const float* __restrict__ abc,        // K*3
    const float* __restrict__ graphs,     // NSG*K*K
    const float* __restrict__ w_real,     // NSG*K*K
    const float* __restrict__ w_imag,     // NSG*K*K
    const float* __restrict__ b_real,     // NSG*K
    const float* __restrict__ b_imag,     // NSG*K
    float* __restrict__ Mout,             // B*E*E
    float* __restrict__ bbout,            // B*E
    float* __restrict__ tabc)             // B*K*3
{
    const int b = blockIdx.x;
    const int t = threadIdx.x;
    const int sg = space_group[b] - 1;

    __shared__ float adjL[KK * KK];
    __shared__ float wrL[KK * KK];
    __shared__ float wiL[KK * KK];

    const float* adjG = graphs + (size_t)sg * KK * KK;
    const float* wrG  = w_real + (size_t)sg * KK * KK;
    const float* wiG  = w_imag + (size_t)sg * KK * KK;
    for (int idx = t; idx < KK * KK; idx += 256) {
        adjL[idx] = adjG[idx];
        wrL[idx]  = wrG[idx];
        wiL[idx]  = wiG[idx];
    }
    __syncthreads();

    // each thread: row i = t>>2, 16 columns starting at (t&3)*16
    const int i  = t >> 2;
    const int f0 = (t & 3) * 16;
    float cr[16], ci[16];
#pragma unroll
    for (int c = 0; c < 16; ++c) { cr[c] = 0.f; ci[c] = 0.f; }
    for (int k = 0; k < KK; ++k) {
        const float a = adjL[i * KK + k];
#pragma unroll
        for (int c = 0; c < 16; ++c) {
            cr[c] += a * wrL[k * KK + f0 + c];
            ci[c] += a * wiL[k * KK + f0 + c];
        }
    }
    float* Mb = Mout + (size_t)b * EE * EE;
#pragma unroll
    for (int c = 0; c < 16; ++c) {
        const int f = f0 + c;
        Mb[i * EE + f]               = cr[c];
        Mb[i * EE + (KK + f)]        = ci[c];
        Mb[(KK + i) * EE + f]        = -ci[c];
        Mb[(KK + i) * EE + (KK + f)] = cr[c];
    }
    if (t < EE) {
        bbout[b * EE + t] = (t < KK) ? b_real[sg * KK + t] : b_imag[sg * KK + (t - KK)];
    }
    if (t < KK) {
        const float a0 = abc[t * 3 + 0], a1 = abc[t * 3 + 1], a2 = abc[t * 3 + 2];
        const float* R = recip + b * 9;
#pragma unroll
        for (int d = 0; d < 3; ++d) {
            tabc[((size_t)b * KK + t) * 3 + d] = a0 * R[d * 3 + 0] + a1 * R[d * 3 + 1] + a2 * R[d * 3 + 2];
        }
    }
}

// ---------------- transpose W2 (E x E) ----------------
__global__ __launch_bounds__(256) void w2t_kernel(const float* __restrict__ W2,
                                                  float* __restrict__ W2T) {
    const int idx = blockIdx.x * 256 + threadIdx.x;  // 0..E*E-1
    const int e = idx / EE, f = idx % EE;
    W2T[f * EE + e] = W2[e * EE + f];
}

// ---------------- main fused kernel ----------------
__global__ __launch_bounds__(256) void main_kernel(
    const float* __restrict__ pos,    // B*N*3
    const float* __restrict__ Mall,   // B*E*E
    const float* __restrict__ bball,  // B*E
    const float* __restrict__ tabc,   // B*K*3
    const float* __restrict__ W2T,    // E*E
    const float* __restrict__ b2,     // E
    const float* __restrict__ gamma,  // E
    const float* __restrict__ beta,   // E
    float* __restrict__ out)          // B*N*E
{
    const int blk = blockIdx.x;
    const int b  = blk >> 5;            // N/TN == 32
    const int n0 = (blk & 31) * TN;
    const int t  = threadIdx.x;
    const int ty = t >> 4;              // 0..15
    const int tx = t & 15;              // 0..15
    const int f0 = tx * 8;

    __shared__ float A[TN][EE + 1];
    __shared__ float X[TN][EE + 1];
    __shared__ float tab[KK * 3];
    __shared__ float pp[TN * 3];

    for (int idx = t; idx < KK * 3; idx += 256) tab[idx] = tabc[(size_t)b * KK * 3 + idx];
    for (int idx = t; idx < TN * 3; idx += 256) pp[idx] = pos[((size_t)b * NN + n0) * 3 + idx];
    __syncthreads();

    // phases -> cos | sin
    for (int idx = t; idx < TN * KK; idx += 256) {
        const int r = idx >> 6;
        const int k = idx & 63;
        const float ph = 6.28318530717958647692f *
            (pp[r * 3 + 0] * tab[k * 3 + 0] + pp[r * 3 + 1] * tab[k * 3 + 1] +
             pp[r * 3 + 2] * tab[k * 3 + 2]);
        float s, c;
        __sincosf(ph, &s, &c);
        A[r][k] = c;
        A[r][KK + k] = s;
    }
    __syncthreads();

    // ---- matmul1: x_pre = A @ M + bb ----
    const float* Mb = Mall + (size_t)b * EE * EE;
    float acc0[8], acc1[8];
#pragma unroll
    for (int c = 0; c < 8; ++c) { acc0[c] = 0.f; acc1[c] = 0.f; }
    for (int j = 0; j < EE; ++j) {
        const float a0 = A[ty][j];
        const float a1 = A[ty + 16][j];
        const float4* m4 = reinterpret_cast<const float4*>(Mb + j * EE + f0);
        const float4 m0 = m4[0];
        const float4 m1 = m4[1];
        acc0[0] += a0 * m0.x; acc0[1] += a0 * m0.y; acc0[2] += a0 * m0.z; acc0[3] += a0 * m0.w;
        acc0[4] += a0 * m1.x; acc0[5] += a0 * m1.y; acc0[6] += a0 * m1.z; acc0[7] += a0 * m1.w;
        acc1[0] += a1 * m0.x; acc1[1] += a1 * m0.y; acc1[2] += a1 * m0.z; acc1[3] += a1 * m0.w;
        acc1[4] += a1 * m1.x; acc1[5] += a1 * m1.y; acc1[6] += a1 * m1.z; acc1[7] += a1 * m1.w;
    }
    // bias + silu -> X
    {
        const float* bbp = bball + b * EE + f0;
#pragma unroll
        for (int c = 0; c < 8; ++c) {
            const float v0 = acc0[c] + bbp[c];
            const float v1 = acc1[c] + bbp[c];
            X[ty][f0 + c]      = v0 / (1.f + __expf(-v0));
            X[ty + 16][f0 + c] = v1 / (1.f + __expf(-v1));
        }
    }
    __syncthreads();

    // ---- matmul2: y = X @ W2T + b2 ----
    float y0[8], y1[8];
#pragma unroll
    for (int c = 0; c < 8; ++c) { y0[c] = 0.f; y1[c] = 0.f; }
    for (int j = 0; j < EE; ++j) {
        const float a0 = X[ty][j];
        const float a1 = X[ty + 16][j];
        const float4* w4 = reinterpret_cast<const float4*>(W2T + j * EE + f0);
        const float4 w0 = w4[0];
        const float4 w1 = w4[1];
        y0[0] += a0 * w0.x; y0[1] += a0 * w0.y; y0[2] += a0 * w0.z; y0[3] += a0 * w0.w;
        y0[4] += a0 * w1.x; y0[5] += a0 * w1.y; y0[6] += a0 * w1.z; y0[7] += a0 * w1.w;
        y1[0] += a1 * w0.x; y1[1] += a1 * w0.y; y1[2] += a1 * w0.z; y1[3] += a1 * w0.w;
        y1[4] += a1 * w1.x; y1[5] += a1 * w1.y; y1[6] += a1 * w1.z; y1[7] += a1 * w1.w;
    }
#pragma unroll
    for (int c = 0; c < 8; ++c) {
        y0[c] += b2[f0 + c];
        y1[c] += b2[f0 + c];
    }

    // ---- LayerNorm over E: 16 lanes (same ty) cover the 128 features ----
    float s0 = 0.f, q0 = 0.f, s1 = 0.f, q1 = 0.f;
#pragma unroll
    for (int c = 0; c < 8; ++c) {
        s0 += y0[c]; q0 += y0[c] * y0[c];
        s1 += y1[c]; q1 += y1[c] * y1[c];
    }
#pragma unroll
    for (int m = 1; m < 16; m <<= 1) {
        s0 += __shfl_xor(s0, m);
        q0 += __shfl_xor(q0, m);
        s1 += __shfl_xor(s1, m);
        q1 += __shfl_xor(q1, m);
    }
    const float inv = 1.f / EE;
    const float mu0 = s0 * inv, mu1 = s1 * inv;
    const float rs0 = rsqrtf(fmaxf(q0 * inv - mu0 * mu0, 0.f) + 1e-5f);
    const float rs1 = rsqrtf(fmaxf(q1 * inv - mu1 * mu1, 0.f) + 1e-5f);

    float* o0 = out + ((size_t)b * NN + n0 + ty) * EE + f0;
    float* o1 = out + ((size_t)b * NN + n0 + ty + 16) * EE + f0;
#pragma unroll
    for (int c = 0; c < 8; ++c) {
        const float g = gamma[f0 + c], be = beta[f0 + c];
        o0[c] = (y0[c] - mu0) * rs0 * g + be;
        o1[c] = (y1[c] - mu1) * rs1 * g + be;
    }
}

extern "C" void kernel_launch(void* const* d_in, const int* in_sizes, int n_in,
                              void* d_out, int out_size, void* d_ws, size_t ws_size,
                              hipStream_t stream) {
    const float* pos    = (const float*)d_in[0];
    const float* recip  = (const float*)d_in[1];
    const int*   sgp    = (const int*)d_in[2];
    const float* abc    = (const float*)d_in[3];
    const float* graphs = (const float*)d_in[4];
    const float* wr     = (const float*)d_in[5];
    const float* wi     = (const float*)d_in[6];
    const float* br     = (const float*)d_in[7];
    const float* bi     = (const float*)d_in[8];
    const float* W2     = (const float*)d_in[9];
    const float* b2     = (const float*)d_in[10];
    const float* gm     = (const float*)d_in[11];
    const float* bt     = (const float*)d_in[12];
    float* out = (float*)d_out;

    float* ws    = (float*)d_ws;
    float* Mall  = ws;                               // B*E*E
    float* bball = Mall + (size_t)BB * EE * EE;      // B*E
    float* tabc  = bball + (size_t)BB * EE;          // B*K*3
    float* W2T   = tabc + (size_t)BB * KK * 3;       // E*E

    hipLaunchKernelGGL(prep_kernel, dim3(BB), dim3(256), 0, stream,
                       recip, sgp, abc, graphs, wr, wi, br, bi, Mall, bball, tabc);
    hipLaunchKernelGGL(w2t_kernel, dim3(EE * EE / 256), dim3(256), 0, stream, W2, W2T);
    hipLaunchKernelGGL(main_kernel, dim3(BB * NN / TN), dim3(256), 0, stream,
                       pos, Mall, bball, tabc, W2T, b2, gm, bt, out);
}

// Round 2
// 81.144 us; speedup vs baseline: 6.2240x; 6.2240x over previous
//
#include <hip/hip_runtime.h>
#include <math.h>

#define BB 256
#define NN 1024
#define KK 64
#define EE 128
#define TM 64   // rows per block in main kernel

typedef _Float16 half8 __attribute__((ext_vector_type(8)));
typedef float f32x4 __attribute__((ext_vector_type(4)));

// swizzled half-index for a [rows][128] f16 LDS tile: XOR 16B-slot bits by row&7
__device__ __forceinline__ int swz(int row, int halfcol) {
    return (row * EE + halfcol) ^ ((row & 7) << 3);
}

// ---------------- prep: per-batch combined matrix Mt (f16, [f][j] = M[j][f]), bias, t_abc ----------------
// C = adj @ (w_real + i w_imag); M = [[Cr, Ci], [-Ci, Cr]]; x_pre = [cos|sin] @ M + [br|bi]
__global__ __launch_bounds__(256) void prep_kernel(
    const float* __restrict__ recip,      // B*9
    const int* __restrict__ space_group,  // B
    const float* __restrict__ abc,        // K*3
    const float* __restrict__ graphs,     // NSG*K*K
    const float* __restrict__ w_real,     // NSG*K*K
    const float* __restrict__ w_imag,     // NSG*K*K
    const float* __restrict__ b_real,     // NSG*K
    const float* __restrict__ b_imag,     // NSG*K
    _Float16* __restrict__ Mt,            // B*E*E  (col-major M, i.e. Mt[f][j] = M[j][f])
    float* __restrict__ bbout,            // B*E
    float* __restrict__ tabc)             // B*K*3
{
    const int b = blockIdx.x;
    const int t = threadIdx.x;
    const int sg = space_group[b] - 1;

    __shared__ float adjL[KK * KK];
    __shared__ float wrL[KK * KK];
    __shared__ float wiL[KK * KK];

    const float* adjG = graphs + (size_t)sg * KK * KK;
    const float* wrG  = w_real + (size_t)sg * KK * KK;
    const float* wiG  = w_imag + (size_t)sg * KK * KK;
    for (int idx = t; idx < KK * KK; idx += 256) {
        adjL[idx] = adjG[idx];
        wrL[idx]  = wrG[idx];
        wiL[idx]  = wiG[idx];
    }
    __syncthreads();

    // thread: C-row i = t>>2, 16 C-cols starting at (t&3)*16
    const int i  = t >> 2;
    const int f0 = (t & 3) * 16;
    float cr[16], ci[16];
#pragma unroll
    for (int c = 0; c < 16; ++c) { cr[c] = 0.f; ci[c] = 0.f; }
    for (int k = 0; k < KK; ++k) {
        const float a = adjL[i * KK + k];
#pragma unroll
        for (int c = 0; c < 16; ++c) {
            cr[c] += a * wrL[k * KK + f0 + c];
            ci[c] += a * wiL[k * KK + f0 + c];
        }
    }
    _Float16* Mb = Mt + (size_t)b * EE * EE;
#pragma unroll
    for (int c = 0; c < 16; ++c) {
        const int f = f0 + c;
        // Mt[f][j]: f<64 row: [Cr[.][f] | -Ci[.][f]] ; f>=64 row: [Ci[.][f-64] | Cr[.][f-64]]
        Mb[f * EE + i]               = (_Float16)cr[c];
        Mb[f * EE + KK + i]          = (_Float16)(-ci[c]);
        Mb[(KK + f) * EE + i]        = (_Float16)ci[c];
        Mb[(KK + f) * EE + KK + i]   = (_Float16)cr[c];
    }
    if (t < EE) {
        bbout[b * EE + t] = (t < KK) ? b_real[sg * KK + t] : b_imag[sg * KK + (t - KK)];
    }
    if (t < KK) {
        const float a0 = abc[t * 3 + 0], a1 = abc[t * 3 + 1], a2 = abc[t * 3 + 2];
        const float* R = recip + b * 9;
#pragma unroll
        for (int d = 0; d < 3; ++d) {
            tabc[((size_t)b * KK + t) * 3 + d] = a0 * R[d * 3 + 0] + a1 * R[d * 3 + 1] + a2 * R[d * 3 + 2];
        }
    }
}

// ---------------- convert W2 to f16 (row-major kept: W2h[f][j] = W2[f][j]) ----------------
__global__ __launch_bounds__(256) void w2conv_kernel(const float* __restrict__ W2,
                                                     _Float16* __restrict__ W2h) {
    const int idx = blockIdx.x * 256 + threadIdx.x;
    W2h[idx] = (_Float16)W2[idx];
}

// ---------------- main fused MFMA kernel ----------------
__global__ __launch_bounds__(256) void main_kernel(
    const float* __restrict__ pos,      // B*N*3
    const _Float16* __restrict__ Mt,    // B*E*E f16
    const float* __restrict__ bball,    // B*E
    const float* __restrict__ tabc,     // B*K*3
    const _Float16* __restrict__ W2h,   // E*E f16
    const float* __restrict__ b2,       // E
    const float* __restrict__ gamma,    // E
    const float* __restrict__ beta,     // E
    float* __restrict__ out)            // B*N*E
{
    const int blk = blockIdx.x;
    const int b  = blk >> 4;            // 16 blocks per batch
    const int n0 = (blk & 15) * TM;
    const int t  = threadIdx.x;
    const int w    = t >> 6;            // wave 0..3 -> rows w*16..w*16+15
    const int lane = t & 63;
    const int ln15 = lane & 15;
    const int kg   = lane >> 4;         // 0..3

    __shared__ __align__(16) _Float16 Bt[EE * EE];   // 32KB: Mt then W2h
    __shared__ __align__(16) _Float16 AX[TM * EE];   // 16KB: A (cos|sin) then X (silu)
    __shared__ float tab[KK * 3];
    __shared__ float pp[TM * 3];

    // ---- stage Mt (swizzled) + tab + pos ----
    {
        const uint4* src = (const uint4*)(Mt + (size_t)b * EE * EE);
#pragma unroll
        for (int i = 0; i < 8; ++i) {
            const int c16 = t + i * 256;        // 16B-chunk id, 2048 total
            const int row = c16 >> 4;
            const int off = (c16 & 15) << 3;
            *(uint4*)&Bt[swz(row, off)] = src[c16];
        }
    }
    for (int idx = t; idx < KK * 3; idx += 256) tab[idx] = tabc[(size_t)b * KK * 3 + idx];
    for (int idx = t; idx < TM * 3; idx += 256) pp[idx] = pos[((size_t)b * NN + n0) * 3 + idx];
    __syncthreads();

    // ---- phases -> A = [cos | sin] (f16, swizzled), rows are wave-local ----
    {
        const int r = t >> 2;          // 0..63
        const int q = t & 3;           // k-quarter (16 k's each? no: 64/4 = 16) -> k in [q*16, q*16+16)
        const float px = pp[r * 3 + 0], py = pp[r * 3 + 1], pz = pp[r * 3 + 2];
#pragma unroll
        for (int g = 0; g < 2; ++g) {
            const int k0 = q * 16 + g * 8;
            _Float16 cbuf[8], sbuf[8];
#pragma unroll
            for (int j = 0; j < 8; ++j) {
                const int k = k0 + j;
                const float ph = 6.28318530717958647692f *
                    (px * tab[k * 3 + 0] + py * tab[k * 3 + 1] + pz * tab[k * 3 + 2]);
                float s, c;
                __sincosf(ph, &s, &c);
                cbuf[j] = (_Float16)c;
                sbuf[j] = (_Float16)s;
            }
            *(uint4*)&AX[swz(r, k0)]      = *(uint4*)cbuf;
            *(uint4*)&AX[swz(r, KK + k0)] = *(uint4*)sbuf;
        }
    }
    __syncthreads();

    const int arow = w * 16 + ln15;     // A-operand row for this lane

    // ---- matmul1: x_pre = A @ M ----
    half8 afrag[4];
#pragma unroll
    for (int kc = 0; kc < 4; ++kc)
        afrag[kc] = *(const half8*)&AX[swz(arow, kc * 32 + kg * 8)];

    f32x4 acc[8];
#pragma unroll
    for (int nt = 0; nt < 8; ++nt) {
        f32x4 a = {0.f, 0.f, 0.f, 0.f};
        const int n = nt * 16 + ln15;
#pragma unroll
        for (int kc = 0; kc < 4; ++kc) {
            const half8 bf = *(const half8*)&Bt[swz(n, kc * 32 + kg * 8)];
            a = __builtin_amdgcn_mfma_f32_16x16x32_f16(afrag[kc], bf, a, 0, 0, 0);
        }
        acc[nt] = a;
    }

    // ---- bias + silu -> X (f16, swizzled; rows wave-local) ----
#pragma unroll
    for (int nt = 0; nt < 8; ++nt) {
        const int col = nt * 16 + ln15;
        const float bbv = bball[b * EE + col];
#pragma unroll
        for (int r2 = 0; r2 < 4; ++r2) {
            const float v = acc[nt][r2] + bbv;
            const float xv = v / (1.f + __expf(-v));
            const int rr = w * 16 + kg * 4 + r2;    // D layout: row=(lane>>4)*4+r2, col=lane&15
            AX[swz(rr, col)] = (_Float16)xv;
        }
    }
    __syncthreads();

    // ---- stage W2h into Bt (overwrites M; all waves done with it) ----
    {
        const uint4* src = (const uint4*)W2h;
#pragma unroll
        for (int i = 0; i < 8; ++i) {
            const int c16 = t + i * 256;
            const int row = c16 >> 4;
            const int off = (c16 & 15) << 3;
            *(uint4*)&Bt[swz(row, off)] = src[c16];
        }
    }
    __syncthreads();

    // ---- matmul2: y = X @ W2^T ----
    half8 a2[4];
#pragma unroll
    for (int kc = 0; kc < 4; ++kc)
        a2[kc] = *(const half8*)&AX[swz(arow, kc * 32 + kg * 8)];

    f32x4 acc2[8];
#pragma unroll
    for (int nt = 0; nt < 8; ++nt) {
        f32x4 a = {0.f, 0.f, 0.f, 0.f};
        const int n = nt * 16 + ln15;
#pragma unroll
        for (int kc = 0; kc < 4; ++kc) {
            const half8 bf = *(const half8*)&Bt[swz(n, kc * 32 + kg * 8)];
            a = __builtin_amdgcn_mfma_f32_16x16x32_f16(a2[kc], bf, a, 0, 0, 0);
        }
        acc2[nt] = a;
    }

    // ---- + b2, LayerNorm over E, write out ----
    float y[8][4];
    float s[4] = {0.f, 0.f, 0.f, 0.f}, q[4] = {0.f, 0.f, 0.f, 0.f};
#pragma unroll
    for (int nt = 0; nt < 8; ++nt) {
        const int col = nt * 16 + ln15;
        const float b2v = b2[col];
#pragma unroll
        for (int r2 = 0; r2 < 4; ++r2) {
            const float v = acc2[nt][r2] + b2v;
            y[nt][r2] = v;
            s[r2] += v;
            q[r2] += v * v;
        }
    }
#pragma unroll
    for (int m = 1; m < 16; m <<= 1) {
#pragma unroll
        for (int r2 = 0; r2 < 4; ++r2) {
            s[r2] += __shfl_xor(s[r2], m);
            q[r2] += __shfl_xor(q[r2], m);
        }
    }
    float mu[4], rs[4];
    const float inv = 1.f / EE;
#pragma unroll
    for (int r2 = 0; r2 < 4; ++r2) {
        mu[r2] = s[r2] * inv;
        rs[r2] = rsqrtf(fmaxf(q[r2] * inv - mu[r2] * mu[r2], 0.f) + 1e-5f);
    }
#pragma unroll
    for (int nt = 0; nt < 8; ++nt) {
        const int col = nt * 16 + ln15;
        const float g  = gamma[col];
        const float be = beta[col];
#pragma unroll
        for (int r2 = 0; r2 < 4; ++r2) {
            const int rr = w * 16 + kg * 4 + r2;
            out[((size_t)b * NN + n0 + rr) * EE + col] = (y[nt][r2] - mu[r2]) * rs[r2] * g + be;
        }
    }
}

extern "C" void kernel_launch(void* const* d_in, const int* in_sizes, int n_in,
                              void* d_out, int out_size, void* d_ws, size_t ws_size,
                              hipStream_t stream) {
    const float* pos    = (const float*)d_in[0];
    const float* recip  = (const float*)d_in[1];
    const int*   sgp    = (const int*)d_in[2];
    const float* abc    = (const float*)d_in[3];
    const float* graphs = (const float*)d_in[4];
    const float* wr     = (const float*)d_in[5];
    const float* wi     = (const float*)d_in[6];
    const float* br     = (const float*)d_in[7];
    const float* bi     = (const float*)d_in[8];
    const float* W2     = (const float*)d_in[9];
    const float* b2     = (const float*)d_in[10];
    const float* gm     = (const float*)d_in[11];
    const float* bt     = (const float*)d_in[12];
    float* out = (float*)d_out;

    char* ws = (char*)d_ws;
    _Float16* Mt   = (_Float16*)ws;                                   // B*E*E f16 = 8388608 B
    _Float16* W2h  = (_Float16*)(ws + (size_t)BB * EE * EE * 2);      // E*E f16  = 32768 B
    float*    bball= (float*)(ws + (size_t)BB * EE * EE * 2 + 32768); // B*E f32
    float*    tabc = bball + (size_t)BB * EE;                         // B*K*3 f32

    hipLaunchKernelGGL(prep_kernel, dim3(BB), dim3(256), 0, stream,
                       recip, sgp, abc, graphs, wr, wi, br, bi, Mt, bball, tabc);
    hipLaunchKernelGGL(w2conv_kernel, dim3(EE * EE / 256), dim3(256), 0, stream, W2, W2h);
    hipLaunchKernelGGL(main_kernel, dim3(BB * NN / TM), dim3(256), 0, stream,
                       pos, Mt, bball, tabc, W2h, b2, gm, bt, out);
}